// Round 10
// baseline (66.580 us; speedup 1.0000x reference)
//
#include <hip/hip_runtime.h>
#include <hip/hip_bf16.h>
#include <stdint.h>

#define NN 1024
#define EMBED 256
#define SLOPE 0.2f

typedef __attribute__((ext_vector_type(8))) short short8;
typedef __attribute__((ext_vector_type(4))) float f32x4;

__device__ __forceinline__ unsigned short f32_to_bf16(float f) {
    unsigned int u = __float_as_uint(f);
    unsigned int r = (u + 0x7FFFu + ((u >> 16) & 1u)) >> 16;
    return (unsigned short)r;
}
__device__ __forceinline__ float bf16_to_f32(unsigned short h) {
    return __uint_as_float(((unsigned int)h) << 16);
}

template <int CTRL>
__device__ __forceinline__ float dpp_mov(float x) {
    int r = __builtin_amdgcn_update_dpp(0, __float_as_int(x), CTRL, 0xF, 0xF, true);
    return __int_as_float(r);
}
__device__ __forceinline__ float group32_sum(float v) {
    v += dpp_mov<0xB1>(v);    // + lane^1
    v += dpp_mov<0x4E>(v);    // + lane^2
    v += dpp_mov<0x141>(v);   // row_half_mirror -> sum over 8
    v += dpp_mov<0x140>(v);   // row_mirror      -> sum over 16
    v += __shfl_xor(v, 16);   // -> sum over 32
    return v;
}

// ---------------------------------------------------------------------------
// ONE kernel, 256 blocks x 256 threads, zero inter-block communication.
// Block b owns destination rows [4b, 4b+4):
//   P0: stream edge list, build 4-row adjacency bitmask in LDS (dedupes).
//   P1: compact to per-row neighbor lists (wave w -> row w).
//   P2: gr for the 4 own rows: MFMA (16-row padded A) @ W_r -> grL (f32).
//   P3: two sub-iters of 2 rows: gather <=128 neighbor h-rows, MFMA @ W_l,
//       gl tile -> LDS bf16; then DPP online-softmax attention from LDS.
// Redundant gl compute (~16x) trades FLOPs (cheap, matrix cores) for the
// elimination of the producer->consumer kernel boundary (expensive).
// ---------------------------------------------------------------------------
__global__ __launch_bounds__(256, 1) void k_all(const float* __restrict__ h,
                                                const int* __restrict__ ei, int E,
                                                const float* __restrict__ Wl,
                                                const float* __restrict__ Wr,
                                                const float* __restrict__ attn_w,
                                                float* __restrict__ out) {
    const int blk = blockIdx.x;
    const int t = threadIdx.x;
    const int rbase = blk * 4;
    const int w = t >> 6, lane = t & 63;
    const int l16 = lane & 15, g = lane >> 4;

    __shared__ unsigned int maskL[128];
    __shared__ int nbrL[4][64];
    __shared__ int cntL[4];
    __shared__ int cmap[128];
    __shared__ __align__(16) unsigned short Ast[128 * 40];   // [m][k] bf16, 80B rows
    __shared__ __align__(16) unsigned short Bst[256 * 40];   // [n][k] bf16 (B^T)
    __shared__ float grL[4 * 264];
    __shared__ unsigned short glL[128 * 272];                // [e][d] bf16

    // ---------------- P0: adjacency bitmask for 4 rows -----------------------
    if (t < 128) maskL[t] = 0u;
    __syncthreads();
    {
        const int4* ei4 = (const int4*)ei;
        const int nvec = E >> 1;
        int base = 0;
        for (; base + 2048 <= nvec; base += 2048) {
#pragma unroll 8
            for (int u = 0; u < 8; ++u) {
                int4 v = ei4[base + u * 256 + t];
                int r0 = v.x - rbase;
                if ((unsigned)r0 < 4u)
                    atomicOr(&maskL[r0 * 32 + ((unsigned)v.y >> 5)], 1u << (v.y & 31));
                int r1 = v.z - rbase;
                if ((unsigned)r1 < 4u)
                    atomicOr(&maskL[r1 * 32 + ((unsigned)v.w >> 5)], 1u << (v.w & 31));
            }
        }
        for (int idx = base + t; idx < nvec; idx += 256) {
            int4 v = ei4[idx];
            int r0 = v.x - rbase;
            if ((unsigned)r0 < 4u)
                atomicOr(&maskL[r0 * 32 + ((unsigned)v.y >> 5)], 1u << (v.y & 31));
            int r1 = v.z - rbase;
            if ((unsigned)r1 < 4u)
                atomicOr(&maskL[r1 * 32 + ((unsigned)v.w >> 5)], 1u << (v.w & 31));
        }
        if ((E & 1) && t == 0) {
            int r = ei[2 * (E - 1)] - rbase, c = ei[2 * (E - 1) + 1];
            if ((unsigned)r < 4u)
                atomicOr(&maskL[r * 32 + ((unsigned)c >> 5)], 1u << (c & 31));
        }
    }
    __syncthreads();

    // ---------------- P1: compact row w (wave w) -----------------------------
    {
        unsigned int wd = (lane < 32) ? maskL[w * 32 + lane] : 0u;
        int c = __popc(wd);
        int pre = c;
#pragma unroll
        for (int d = 1; d < 32; d <<= 1) {
            int v = __shfl_up(pre, d);
            if (lane >= d) pre += v;
        }
        int tot = __shfl(pre, 31);
        int off = pre - c;
        if (lane == 0) cntL[w] = tot > 64 ? 64 : tot;
        while (wd) {
            int b = __builtin_ctz(wd);
            wd &= wd - 1;
            if (off < 64) nbrL[w][off] = lane * 32 + b;
            ++off;
        }
    }

    // ---------------- P2: gr for 4 own rows ----------------------------------
    {
        f32x4 accg[4];
#pragma unroll
        for (int nf = 0; nf < 4; ++nf) accg[nf] = (f32x4)(0.f);
        for (int kt = 0; kt < 8; ++kt) {
            const int k0 = kt * 32;
            __syncthreads();
            if (t < 128) {   // A: 16 rows (own 4, repeated) x 32 k
                int m = t >> 3, q = t & 7;
                float4 v = *(const float4*)(h + (size_t)(rbase + (m & 3)) * EMBED + k0 + 4 * q);
                int b = m * 40 + 4 * q;
                Ast[b + 0] = f32_to_bf16(v.x); Ast[b + 1] = f32_to_bf16(v.y);
                Ast[b + 2] = f32_to_bf16(v.z); Ast[b + 3] = f32_to_bf16(v.w);
            }
            {   // B^T: W_r k-tile [32k x 256n] -> Bst[n][k]
                int kk = t >> 3, f = t & 7;
                const float* src = Wr + (size_t)(k0 + kk) * EMBED;
#pragma unroll
                for (int j = 0; j < 8; ++j) {
                    int n0 = (f + 8 * j) * 4;
                    float4 v = *(const float4*)(src + n0);
                    Bst[(n0 + 0) * 40 + kk] = f32_to_bf16(v.x);
                    Bst[(n0 + 1) * 40 + kk] = f32_to_bf16(v.y);
                    Bst[(n0 + 2) * 40 + kk] = f32_to_bf16(v.z);
                    Bst[(n0 + 3) * 40 + kk] = f32_to_bf16(v.w);
                }
            }
            __syncthreads();
            short8 a = *(const short8*)&Ast[l16 * 40 + g * 8];
#pragma unroll
            for (int nf = 0; nf < 4; ++nf) {
                short8 b = *(const short8*)&Bst[(64 * w + nf * 16 + l16) * 40 + g * 8];
                accg[nf] = __builtin_amdgcn_mfma_f32_16x16x32_bf16(a, b, accg[nf], 0, 0, 0);
            }
        }
        if (g == 0) {   // rows 0..3 = own rows; col = 64w + nf*16 + l16
#pragma unroll
            for (int nf = 0; nf < 4; ++nf)
#pragma unroll
                for (int p = 0; p < 4; ++p)
                    grL[p * 264 + 64 * w + nf * 16 + l16] = accg[nf][p];
        }
    }

    // ---------------- P3: two sub-iters of 2 rows each -----------------------
    const float aw = attn_w[t & 31];
    for (int s = 0; s < 2; ++s) {
        __syncthreads();
        const int c0 = cntL[2 * s], c1 = cntL[2 * s + 1];
        if (t < 128) {
            int v;
            if (t < c0) v = nbrL[2 * s][t];
            else if (t < c0 + c1) v = nbrL[2 * s + 1][t - c0];
            else v = rbase;     // pad rows: harmless, never read
            cmap[t] = v;
        }

        f32x4 acc[8][4];
#pragma unroll
        for (int mt = 0; mt < 8; ++mt)
#pragma unroll
            for (int nf = 0; nf < 4; ++nf) acc[mt][nf] = (f32x4)(0.f);

        for (int kt = 0; kt < 8; ++kt) {
            const int k0 = kt * 32;
            __syncthreads();   // covers cmap build (kt=0) and prev compute
            {   // A: gathered 128 rows x 32 k
                int m = t >> 1, j0 = (t & 1) * 16;
                const float* src = h + (size_t)cmap[m] * EMBED + k0 + j0;
                float4 v0 = *(const float4*)(src + 0);
                float4 v1 = *(const float4*)(src + 4);
                float4 v2 = *(const float4*)(src + 8);
                float4 v3 = *(const float4*)(src + 12);
                int b = m * 40 + j0;
                Ast[b + 0]  = f32_to_bf16(v0.x); Ast[b + 1]  = f32_to_bf16(v0.y);
                Ast[b + 2]  = f32_to_bf16(v0.z); Ast[b + 3]  = f32_to_bf16(v0.w);
                Ast[b + 4]  = f32_to_bf16(v1.x); Ast[b + 5]  = f32_to_bf16(v1.y);
                Ast[b + 6]  = f32_to_bf16(v1.z); Ast[b + 7]  = f32_to_bf16(v1.w);
                Ast[b + 8]  = f32_to_bf16(v2.x); Ast[b + 9]  = f32_to_bf16(v2.y);
                Ast[b + 10] = f32_to_bf16(v2.z); Ast[b + 11] = f32_to_bf16(v2.w);
                Ast[b + 12] = f32_to_bf16(v3.x); Ast[b + 13] = f32_to_bf16(v3.y);
                Ast[b + 14] = f32_to_bf16(v3.z); Ast[b + 15] = f32_to_bf16(v3.w);
            }
            {   // B^T: W_l k-tile
                int kk = t >> 3, f = t & 7;
                const float* src = Wl + (size_t)(k0 + kk) * EMBED;
#pragma unroll
                for (int j = 0; j < 8; ++j) {
                    int n0 = (f + 8 * j) * 4;
                    float4 v = *(const float4*)(src + n0);
                    Bst[(n0 + 0) * 40 + kk] = f32_to_bf16(v.x);
                    Bst[(n0 + 1) * 40 + kk] = f32_to_bf16(v.y);
                    Bst[(n0 + 2) * 40 + kk] = f32_to_bf16(v.z);
                    Bst[(n0 + 3) * 40 + kk] = f32_to_bf16(v.w);
                }
            }
            __syncthreads();
            short8 bfr[4];
#pragma unroll
            for (int nf = 0; nf < 4; ++nf)
                bfr[nf] = *(const short8*)&Bst[(64 * w + nf * 16 + l16) * 40 + g * 8];
#pragma unroll
            for (int mt = 0; mt < 8; ++mt) {
                short8 a = *(const short8*)&Ast[(mt * 16 + l16) * 40 + g * 8];
#pragma unroll
                for (int nf = 0; nf < 4; ++nf)
                    acc[mt][nf] = __builtin_amdgcn_mfma_f32_16x16x32_bf16(a, bfr[nf], acc[mt][nf], 0, 0, 0);
            }
        }
        // epilogue: gl tile -> LDS bf16. row = mt*16 + g*4 + p, col = 64w+nf*16+l16
#pragma unroll
        for (int mt = 0; mt < 8; ++mt)
#pragma unroll
            for (int nf = 0; nf < 4; ++nf)
#pragma unroll
                for (int p = 0; p < 4; ++p)
                    glL[(mt * 16 + g * 4 + p) * 272 + 64 * w + nf * 16 + l16] =
                        f32_to_bf16(acc[mt][nf][p]);
        __syncthreads();

        // attention for local rows 0,1 (global rows rbase+2s, rbase+2s+1)
#pragma unroll
        for (int r = 0; r < 2; ++r) {
            const int rg = 2 * s + r;
            const int cntr = r ? c1 : c0;
            const int eb = r ? c0 : 0;
            const float grv = grL[rg * 264 + t];
            float mm = -3e38f, ss = 0.f, ac = 0.f;
            for (int e0 = 0; e0 < cntr; e0 += 4) {
                float cg[4], p4[4];
#pragma unroll
                for (int u = 0; u < 4; ++u) {
                    int e = e0 + u;
                    e = (e < cntr) ? e : cntr - 1;
                    cg[u] = bf16_to_f32(glL[(eb + e) * 272 + t]);
                }
#pragma unroll
                for (int u = 0; u < 4; ++u) {
                    float x = cg[u] + grv;
                    p4[u] = group32_sum((x > 0.f ? x : SLOPE * x) * aw);
                }
                float pm = p4[0];
#pragma unroll
                for (int u = 1; u < 4; ++u)
                    if (e0 + u < cntr) pm = fmaxf(pm, p4[u]);
                float mn = fmaxf(mm, pm);
                float sc = __expf(mm - mn);
                float ev[4];
#pragma unroll
                for (int u = 0; u < 4; ++u)
                    ev[u] = (e0 + u < cntr) ? __expf(p4[u] - mn) : 0.f;
                ss = ss * sc + ((ev[0] + ev[1]) + (ev[2] + ev[3]));
                ac = ac * sc + ((ev[0] * cg[0] + ev[1] * cg[1]) + (ev[2] * cg[2] + ev[3] * cg[3]));
                mm = mn;
            }
            out[(size_t)(rbase + rg) * EMBED + t] = ac / ss;
        }
    }
}

extern "C" void kernel_launch(void* const* d_in, const int* in_sizes, int n_in,
                              void* d_out, int out_size, void* d_ws, size_t ws_size,
                              hipStream_t stream) {
    const float* h  = (const float*)d_in[0];
    const int*   ei = (const int*)d_in[1];
    const float* Wl = (const float*)d_in[2];
    const float* Wr = (const float*)d_in[3];
    const float* aw = (const float*)d_in[4];
    float* out = (float*)d_out;
    const int E = in_sizes[1] / 2;

    k_all<<<256, 256, 0, stream>>>(h, ei, E, Wl, Wr, aw, out);
}

// Round 11
// 49.504 us; speedup vs baseline: 1.3449x; 1.3449x over previous
//
#include <hip/hip_runtime.h>
#include <stdint.h>

#define EMBED 256
#define SLOPE 0.2f
#define WS 40   // LDS row stride in shorts (80 B = 16B multiple -> aligned b128 frags)

typedef __attribute__((ext_vector_type(8))) short short8;
typedef __attribute__((ext_vector_type(4))) float f32x4;

// two f32 -> packed bf16 pair (round-half-up; 2 adds + 1 v_perm)
__device__ __forceinline__ unsigned int pack2_bf16(float lo, float hi) {
    unsigned int ul = __float_as_uint(lo) + 0x8000u;
    unsigned int uh = __float_as_uint(hi) + 0x8000u;
    return __builtin_amdgcn_perm(uh, ul, 0x07060302u);  // {hi[31:16], lo[31:16]}
}

// ---------------------------------------------------------------------------
// ONE kernel, 256 blocks x 512 threads. Block owns dest rows [4b, 4b+4).
//  P0 edge-stream -> 4-row bitmask (LDS, dedupes)
//  P1 compact -> per-row neighbor lists (<=64), cmap per edge-half
//  P2 gr = h_own @ W_r via MFMA (A = W_r^T tile [f][k], B = own rows [i][k])
//  P3 one kt loop: stage W_l^T tile + gathered-h tiles (both halves);
//     MFMA D[f][e]; then per-head scores/softmax/aggregation directly from
//     the accumulator registers (no gl materialization).
// Waves 0-3: edge half 0 (rows 4b,4b+1); waves 4-7: half 1 (rows +2,+3).
// Wave w covers features [w*64, w*64+64): head pair 2w, 2w+1.
// ---------------------------------------------------------------------------
__global__ __launch_bounds__(512, 2) void k_all(const float* __restrict__ h,
                                                const int* __restrict__ ei, int E,
                                                const float* __restrict__ Wl,
                                                const float* __restrict__ Wr,
                                                const float* __restrict__ attn_w,
                                                float* __restrict__ out) {
    const int blk = blockIdx.x;
    const int t = threadIdx.x;
    const int rbase = blk * 4;
    const int ww = t >> 6;       // wave 0..7
    const int sgrp = ww >> 2;    // edge-half this wave computes
    const int w = ww & 3;        // feature quarter
    const int lane = t & 63;
    const int l16 = lane & 15;
    const int g = lane >> 4;

    __shared__ unsigned int maskL[128];
    __shared__ int nbrL[4][64];
    __shared__ int cntL[4];
    __shared__ int cmap[2][128];
    __shared__ __align__(16) unsigned short Wt[256 * WS];     // 20 KB
    __shared__ __align__(16) unsigned short Ht[2][128 * WS];  // 20 KB
    __shared__ __align__(16) unsigned short H4[16 * WS];      // 1.3 KB
    __shared__ float grL[4][256];                             // 4 KB
    __shared__ float scp[2][8][128];                          // 8 KB scores
    __shared__ float aWs[2][8][128];                          // 8 KB softmax wts

    // ---------------- P0: adjacency bitmask --------------------------------
    if (t < 128) maskL[t] = 0u;
    __syncthreads();
    {
        const int4* ei4 = (const int4*)ei;
        const int nvec = E >> 1;
        int base = 0;
        for (; base + 4096 <= nvec; base += 4096) {
#pragma unroll 8
            for (int u = 0; u < 8; ++u) {
                int4 v = ei4[base + u * 512 + t];
                int r0 = v.x - rbase;
                if ((unsigned)r0 < 4u)
                    atomicOr(&maskL[r0 * 32 + ((unsigned)v.y >> 5)], 1u << (v.y & 31));
                int r1 = v.z - rbase;
                if ((unsigned)r1 < 4u)
                    atomicOr(&maskL[r1 * 32 + ((unsigned)v.w >> 5)], 1u << (v.w & 31));
            }
        }
        for (int idx = base + t; idx < nvec; idx += 512) {
            int4 v = ei4[idx];
            int r0 = v.x - rbase;
            if ((unsigned)r0 < 4u)
                atomicOr(&maskL[r0 * 32 + ((unsigned)v.y >> 5)], 1u << (v.y & 31));
            int r1 = v.z - rbase;
            if ((unsigned)r1 < 4u)
                atomicOr(&maskL[r1 * 32 + ((unsigned)v.w >> 5)], 1u << (v.w & 31));
        }
        if ((E & 1) && t == 0) {
            int r = ei[2 * (E - 1)] - rbase, c = ei[2 * (E - 1) + 1];
            if ((unsigned)r < 4u)
                atomicOr(&maskL[r * 32 + ((unsigned)c >> 5)], 1u << (c & 31));
        }
    }
    __syncthreads();

    // ---------------- P1: compact row ww (waves 0-3) ------------------------
    if (ww < 4) {
        unsigned int wd = (lane < 32) ? maskL[ww * 32 + lane] : 0u;
        int c = __popc(wd);
        int pre = c;
#pragma unroll
        for (int d = 1; d < 32; d <<= 1) {
            int v = __shfl_up(pre, d);
            if (lane >= d) pre += v;
        }
        int tot = __shfl(pre, 31);
        int off = pre - c;
        if (lane == 0) cntL[ww] = tot > 64 ? 64 : tot;
        while (wd) {
            int b = __builtin_ctz(wd);
            wd &= wd - 1;
            if (off < 64) nbrL[ww][off] = lane * 32 + b;
            ++off;
        }
    }
    __syncthreads();

    // cmap: edge-half s holds edges of rows 2s, 2s+1 (pad -> rbase, masked later)
    if (t < 256) {
        int s = t >> 7, e = t & 127;
        int c0 = cntL[2 * s], c1 = cntL[2 * s + 1];
        int v = rbase;
        if (e < c0) v = nbrL[2 * s][e];
        else if (e < c0 + c1) v = nbrL[2 * s + 1][e - c0];
        cmap[s][e] = v;
    }

    // ---------------- P2: gr for the 4 own rows -----------------------------
    f32x4 agr[4];
#pragma unroll
    for (int mt = 0; mt < 4; ++mt) agr[mt] = (f32x4)(0.f);
    for (int kt = 0; kt < 8; ++kt) {
        const int k0 = kt * 32;
        __syncthreads();
        {   // W_r^T tile [256f][32k]
            const int f = t >> 1, kk0 = (t & 1) << 4;
            float v[16];
#pragma unroll
            for (int j = 0; j < 16; ++j) v[j] = Wr[(size_t)(k0 + kk0 + j) * EMBED + f];
#pragma unroll
            for (int q = 0; q < 4; ++q)
                *(uint2*)&Wt[f * WS + kk0 + 4 * q] =
                    make_uint2(pack2_bf16(v[4*q], v[4*q+1]), pack2_bf16(v[4*q+2], v[4*q+3]));
        }
        {   // own 4 rows (rows 4..15 zero)
            const int r16 = t >> 5, kk = t & 31;
            float v = (r16 < 4) ? h[(size_t)(rbase + r16) * EMBED + k0 + kk] : 0.f;
            H4[r16 * WS + kk] = (unsigned short)((__float_as_uint(v) + 0x8000u) >> 16);
        }
        __syncthreads();
        short8 b = *(const short8*)&H4[l16 * WS + g * 8];
#pragma unroll
        for (int mt = 0; mt < 4; ++mt) {
            short8 a = *(const short8*)&Wt[(w * 64 + mt * 16 + l16) * WS + g * 8];
            agr[mt] = __builtin_amdgcn_mfma_f32_16x16x32_bf16(a, b, agr[mt], 0, 0, 0);
        }
    }
    if (sgrp == 0 && l16 < 4) {   // redistribute: grL[own row][feature]
#pragma unroll
        for (int mt = 0; mt < 4; ++mt)
#pragma unroll
            for (int p = 0; p < 4; ++p)
                grL[l16][w * 64 + mt * 16 + g * 4 + p] = agr[mt][p];
    }

    // ---------------- P3: gl GEMM, both halves ------------------------------
    f32x4 acc[4][8];
#pragma unroll
    for (int mt = 0; mt < 4; ++mt)
#pragma unroll
        for (int nf = 0; nf < 8; ++nf) acc[mt][nf] = (f32x4)(0.f);

    for (int kt = 0; kt < 8; ++kt) {
        const int k0 = kt * 32;
        __syncthreads();
        {   // W_l^T tile
            const int f = t >> 1, kk0 = (t & 1) << 4;
            float v[16];
#pragma unroll
            for (int j = 0; j < 16; ++j) v[j] = Wl[(size_t)(k0 + kk0 + j) * EMBED + f];
#pragma unroll
            for (int q = 0; q < 4; ++q)
                *(uint2*)&Wt[f * WS + kk0 + 4 * q] =
                    make_uint2(pack2_bf16(v[4*q], v[4*q+1]), pack2_bf16(v[4*q+2], v[4*q+3]));
        }
        {   // gathered h tiles, both halves: ps = t>>8
            const int ps = t >> 8, tt = t & 255;
            const int e = tt >> 1, kk0 = (tt & 1) << 4;
            const float* src = h + (size_t)cmap[ps][e] * EMBED + k0 + kk0;
            float4 v0 = *(const float4*)(src + 0);
            float4 v1 = *(const float4*)(src + 4);
            float4 v2 = *(const float4*)(src + 8);
            float4 v3 = *(const float4*)(src + 12);
            unsigned short* d = &Ht[ps][e * WS + kk0];
            *(uint2*)(d + 0)  = make_uint2(pack2_bf16(v0.x, v0.y), pack2_bf16(v0.z, v0.w));
            *(uint2*)(d + 4)  = make_uint2(pack2_bf16(v1.x, v1.y), pack2_bf16(v1.z, v1.w));
            *(uint2*)(d + 8)  = make_uint2(pack2_bf16(v2.x, v2.y), pack2_bf16(v2.z, v2.w));
            *(uint2*)(d + 12) = make_uint2(pack2_bf16(v3.x, v3.y), pack2_bf16(v3.z, v3.w));
        }
        __syncthreads();
        short8 bf[8];
#pragma unroll
        for (int nf = 0; nf < 8; ++nf)
            bf[nf] = *(const short8*)&Ht[sgrp][(nf * 16 + l16) * WS + g * 8];
#pragma unroll
        for (int mt = 0; mt < 4; ++mt) {
            short8 a = *(const short8*)&Wt[(w * 64 + mt * 16 + l16) * WS + g * 8];
#pragma unroll
            for (int nf = 0; nf < 8; ++nf)
                acc[mt][nf] = __builtin_amdgcn_mfma_f32_16x16x32_bf16(a, bf[nf], acc[mt][nf], 0, 0, 0);
        }
    }

    // ---------------- scores (per head) from registers ----------------------
    const int c0s = cntL[2 * sgrp];
    const int c1s = cntL[2 * sgrp + 1];
    float grv0[16], grv1[16], awv[16];
#pragma unroll
    for (int mt = 0; mt < 4; ++mt)
#pragma unroll
        for (int p = 0; p < 4; ++p) {
            int j = mt * 4 + p;
            int f = w * 64 + mt * 16 + g * 4 + p;
            grv0[j] = grL[2 * sgrp][f];
            grv1[j] = grL[2 * sgrp + 1][f];
            awv[j] = attn_w[f & 31];
        }
#pragma unroll
    for (int nf = 0; nf < 8; ++nf) {
        int e = nf * 16 + l16;
        bool is0 = e < c0s;
        float ph[2] = {0.f, 0.f};   // head 2w (mt 0,1) / head 2w+1 (mt 2,3)
#pragma unroll
        for (int mt = 0; mt < 4; ++mt)
#pragma unroll
            for (int p = 0; p < 4; ++p) {
                int j = mt * 4 + p;
                float gv = is0 ? grv0[j] : grv1[j];
                float x = acc[mt][nf][p] + gv;
                float lr = fmaxf(x, SLOPE * x);       // leaky_relu via max(x, 0.2x)
                ph[mt >> 1] = fmaf(awv[j], lr, ph[mt >> 1]);
            }
#pragma unroll
        for (int hh = 0; hh < 2; ++hh) {
            float v = ph[hh];
            v += __shfl_xor(v, 16);
            v += __shfl_xor(v, 32);
            if (lane < 16) scp[sgrp][2 * w + hh][e] = v;
        }
    }
    __syncthreads();

    // ---------------- softmax: wave ww -> row (ww&3), heads (ww>>2)*4.. -----
    {
        const int r = ww & 3;           // local row 0..3
        const int sr = r >> 1;
        const int eb = (r & 1) ? cntL[2 * sr] : 0;
        const int cr = cntL[r];
        const bool valid = lane < cr;
        const int eidx = eb + (valid ? lane : 0);
#pragma unroll
        for (int hq = 0; hq < 4; ++hq) {
            int hd = (ww >> 2) * 4 + hq;
            float sv = valid ? scp[sr][hd][eidx] : -3e38f;
            float mx = sv;
#pragma unroll
            for (int d = 1; d < 64; d <<= 1) mx = fmaxf(mx, __shfl_xor(mx, d));
            float ev = valid ? __expf(sv - mx) : 0.f;
            float sm = ev;
#pragma unroll
            for (int d = 1; d < 64; d <<= 1) sm += __shfl_xor(sm, d);
            if (valid) aWs[sr][hd][eidx] = ev / sm;
        }
    }
    __syncthreads();

    // ---------------- aggregation from registers ----------------------------
    float av0[2][8], av1[2][8];
#pragma unroll
    for (int nf = 0; nf < 8; ++nf) {
        int e = nf * 16 + l16;
        bool in0 = e < c0s;
        bool in1 = (e >= c0s) && (e < c0s + c1s);
#pragma unroll
        for (int hh = 0; hh < 2; ++hh) {
            float a = aWs[sgrp][2 * w + hh][e];
            av0[hh][nf] = in0 ? a : 0.f;
            av1[hh][nf] = in1 ? a : 0.f;
        }
    }
#pragma unroll
    for (int mt = 0; mt < 4; ++mt) {
        float o0[4], o1[4];
#pragma unroll
        for (int p = 0; p < 4; ++p) {
            float v0 = 0.f, v1 = 0.f;
#pragma unroll
            for (int nf = 0; nf < 8; ++nf) {
                v0 = fmaf(av0[mt >> 1][nf], acc[mt][nf][p], v0);
                v1 = fmaf(av1[mt >> 1][nf], acc[mt][nf][p], v1);
            }
#pragma unroll
            for (int d = 1; d < 16; d <<= 1) {
                v0 += __shfl_xor(v0, d);
                v1 += __shfl_xor(v1, d);
            }
            o0[p] = v0; o1[p] = v1;
        }
        if (l16 == 0) {
            const int f0 = w * 64 + mt * 16 + g * 4;
            *(float4*)&out[(size_t)(rbase + 2 * sgrp) * EMBED + f0] =
                make_float4(o0[0], o0[1], o0[2], o0[3]);
            *(float4*)&out[(size_t)(rbase + 2 * sgrp + 1) * EMBED + f0] =
                make_float4(o1[0], o1[1], o1[2], o1[3]);
        }
    }
}

extern "C" void kernel_launch(void* const* d_in, const int* in_sizes, int n_in,
                              void* d_out, int out_size, void* d_ws, size_t ws_size,
                              hipStream_t stream) {
    const float* h  = (const float*)d_in[0];
    const int*   ei = (const int*)d_in[1];
    const float* Wl = (const float*)d_in[2];
    const float* Wr = (const float*)d_in[3];
    const float* aw = (const float*)d_in[4];
    float* out = (float*)d_out;
    const int E = in_sizes[1] / 2;

    k_all<<<256, 512, 0, stream>>>(h, ei, E, Wl, Wr, aw, out);
}

// Round 12
// 44.935 us; speedup vs baseline: 1.4817x; 1.1017x over previous
//
#include <hip/hip_runtime.h>
#include <stdint.h>

#define EMBED 256
#define SLOPE 0.2f
#define WS 40   // LDS row stride in shorts (80 B -> 16B-aligned b128 frags, 2-way banks)

typedef __attribute__((ext_vector_type(8))) short short8;
typedef __attribute__((ext_vector_type(4))) float f32x4;

// packed bf16 pair: lo -> D[15:0], hi -> D[31:16] (RNE), single VALU op
__device__ __forceinline__ unsigned int cvtpk2(float lo, float hi) {
    unsigned int r;
    asm("v_cvt_pk_bf16_f32 %0, %1, %2" : "=v"(r) : "v"(lo), "v"(hi));
    return r;
}

// ---------------------------------------------------------------------------
// ONE kernel, 256 blocks x 512 threads. Block owns dest rows [4b, 4b+4).
//  P0 edge-stream -> 4-row bitmask (dedupes)
//  P1 compact -> neighbor lists, cmapF[256] (two 128-edge halves), hoF f32
//  P2 gr via VALU once (512 thr x half-k partials into scp, combine -> grL)
//  P3 8x kt: {barrier; write W_l^T + gathered-h bf16 tiles from regs;
//             barrier; issue kt+1 loads; 32 MFMA}  (async-stage pipeline)
//  scores / softmax(in-place scp) / aggregation from acc registers
// Waves 0-3: edge half 0 (rows +0,+1); waves 4-7: half 1. Wave w: f quarter.
// ---------------------------------------------------------------------------
__global__ __launch_bounds__(512, 1) void k_all(const float* __restrict__ h,
                                                const int* __restrict__ ei, int E,
                                                const float* __restrict__ Wl,
                                                const float* __restrict__ Wr,
                                                const float* __restrict__ attn_w,
                                                float* __restrict__ out) {
    const int blk = blockIdx.x;
    const int t = threadIdx.x;
    const int rbase = blk * 4;
    const int ww = t >> 6, lane = t & 63;
    const int sgrp = ww >> 2, w = ww & 3;
    const int l16 = lane & 15, g = lane >> 4;

    __shared__ unsigned int maskL[128];
    __shared__ int nbrL[4][64];
    __shared__ int cntL[4];
    __shared__ int cmapF[256];
    __shared__ __align__(16) unsigned short WtL[256 * WS];   // 20 KB
    __shared__ __align__(16) unsigned short Ht[256 * WS];    // 20 KB
    __shared__ float hoF[4][256];                            // 4 KB
    __shared__ float grL[4][256];                            // 4 KB
    __shared__ float scp[2][8][128];                         // 8 KB (gr partials / scores / weights)

    // ---------------- P0: adjacency bitmask ---------------------------------
    if (t < 128) maskL[t] = 0u;
    __syncthreads();
    {
        const int4* ei4 = (const int4*)ei;
        const int nvec = E >> 1;
        int base = 0;
        for (; base + 4096 <= nvec; base += 4096) {
#pragma unroll 8
            for (int u = 0; u < 8; ++u) {
                int4 v = ei4[base + u * 512 + t];
                int r0 = v.x - rbase;
                if ((unsigned)r0 < 4u)
                    atomicOr(&maskL[r0 * 32 + ((unsigned)v.y >> 5)], 1u << (v.y & 31));
                int r1 = v.z - rbase;
                if ((unsigned)r1 < 4u)
                    atomicOr(&maskL[r1 * 32 + ((unsigned)v.w >> 5)], 1u << (v.w & 31));
            }
        }
        for (int idx = base + t; idx < nvec; idx += 512) {
            int4 v = ei4[idx];
            int r0 = v.x - rbase;
            if ((unsigned)r0 < 4u)
                atomicOr(&maskL[r0 * 32 + ((unsigned)v.y >> 5)], 1u << (v.y & 31));
            int r1 = v.z - rbase;
            if ((unsigned)r1 < 4u)
                atomicOr(&maskL[r1 * 32 + ((unsigned)v.w >> 5)], 1u << (v.w & 31));
        }
        if ((E & 1) && t == 0) {
            int r = ei[2 * (E - 1)] - rbase, c = ei[2 * (E - 1) + 1];
            if ((unsigned)r < 4u)
                atomicOr(&maskL[r * 32 + ((unsigned)c >> 5)], 1u << (c & 31));
        }
    }
    __syncthreads();

    // ---------------- P1: compact row ww (waves 0-3) ------------------------
    if (ww < 4) {
        unsigned int wd = (lane < 32) ? maskL[ww * 32 + lane] : 0u;
        int c = __popc(wd);
        int pre = c;
#pragma unroll
        for (int d = 1; d < 32; d <<= 1) {
            int v = __shfl_up(pre, d);
            if (lane >= d) pre += v;
        }
        int tot = __shfl(pre, 31);
        int off = pre - c;
        if (lane == 0) cntL[ww] = tot > 64 ? 64 : tot;
        while (wd) {
            int b = __builtin_ctz(wd);
            wd &= wd - 1;
            if (off < 64) nbrL[ww][off] = lane * 32 + b;
            ++off;
        }
    }
    __syncthreads();

    // cmapF (threads 0-255) + hoF f32 stage (threads 256-511)
    if (t < 256) {
        int s = t >> 7, e = t & 127;
        int c0 = cntL[2 * s], c1 = cntL[2 * s + 1];
        int v = rbase;
        if (e < c0) v = nbrL[2 * s][e];
        else if (e < c0 + c1) v = nbrL[2 * s + 1][e - c0];
        cmapF[t] = v;
    } else {
        int tt = t - 256;
        int row = tt >> 6, k4 = (tt & 63) << 2;
        *(float4*)&hoF[row][k4] = *(const float4*)&h[(size_t)(rbase + row) * EMBED + k4];
    }
    __syncthreads();

    // ---------------- P2: gr via VALU (once) --------------------------------
    {
        float* prtF = &scp[0][0][0];                 // [2][1024] partials
        const int kh = t >> 8, sub = t & 255;
        const int i = sub >> 6, f0 = (sub & 63) << 2;
        float a0 = 0.f, a1 = 0.f, a2 = 0.f, a3 = 0.f;
        const float* wp = Wr + (size_t)(kh * 128) * EMBED + f0;
        const float* hp = &hoF[i][kh * 128];
#pragma unroll 8
        for (int k = 0; k < 128; ++k) {
            float4 wv = *(const float4*)(wp + (size_t)k * EMBED);
            float hv = hp[k];
            a0 = fmaf(hv, wv.x, a0); a1 = fmaf(hv, wv.y, a1);
            a2 = fmaf(hv, wv.z, a2); a3 = fmaf(hv, wv.w, a3);
        }
        *(float4*)&prtF[kh * 1024 + sub * 4] = make_float4(a0, a1, a2, a3);
    }
    __syncthreads();
    if (t < 256) {
        const float* prtF = &scp[0][0][0];
        float4 p0 = *(const float4*)&prtF[t * 4];
        float4 p1 = *(const float4*)&prtF[1024 + t * 4];
        ((float4*)grL)[t] = make_float4(p0.x + p1.x, p0.y + p1.y, p0.z + p1.z, p0.w + p1.w);
    }

    // gather-row registers (cmapF stable from here)
    const int eH = t >> 3;               // 0..63
    const int qH = (t & 7) << 2;         // k offset 0,4,...,28
    int crow[4];
#pragma unroll
    for (int r = 0; r < 4; ++r) crow[r] = cmapF[eH + r * 64];
    const int kpA = 2 * ww;              // even-k column pair base (rep 0)
    const int kpB = 2 * (ww + 8);        // rep 1
    const int fqW = lane;                // f-quad

    // ---------------- P3: pipelined GEMM loop -------------------------------
    f32x4 acc[4][8];
#pragma unroll
    for (int mt = 0; mt < 4; ++mt)
#pragma unroll
        for (int nf = 0; nf < 8; ++nf) acc[mt][nf] = (f32x4)(0.f);

    float4 wl0, wl1, wl2, wl3, hg0, hg1, hg2, hg3;

#define LOADW(K0) { \
    const float* s0 = Wl + (size_t)((K0) + kpA) * EMBED + 4 * fqW; \
    wl0 = *(const float4*)s0; wl1 = *(const float4*)(s0 + EMBED); \
    const float* s1 = Wl + (size_t)((K0) + kpB) * EMBED + 4 * fqW; \
    wl2 = *(const float4*)s1; wl3 = *(const float4*)(s1 + EMBED); }
#define LOADH(K0) { \
    hg0 = *(const float4*)(h + (size_t)crow[0] * EMBED + (K0) + qH); \
    hg1 = *(const float4*)(h + (size_t)crow[1] * EMBED + (K0) + qH); \
    hg2 = *(const float4*)(h + (size_t)crow[2] * EMBED + (K0) + qH); \
    hg3 = *(const float4*)(h + (size_t)crow[3] * EMBED + (K0) + qH); }

    LOADW(0); LOADH(0);
    for (int kt = 0; kt < 8; ++kt) {
        __syncthreads();                 // previous tile's reads complete
        // write W_l^T tile: rows 4fqW+j (f), cols kpA/kpB (k pairs)
        *(unsigned int*)&WtL[(4 * fqW + 0) * WS + kpA] = cvtpk2(wl0.x, wl1.x);
        *(unsigned int*)&WtL[(4 * fqW + 1) * WS + kpA] = cvtpk2(wl0.y, wl1.y);
        *(unsigned int*)&WtL[(4 * fqW + 2) * WS + kpA] = cvtpk2(wl0.z, wl1.z);
        *(unsigned int*)&WtL[(4 * fqW + 3) * WS + kpA] = cvtpk2(wl0.w, wl1.w);
        *(unsigned int*)&WtL[(4 * fqW + 0) * WS + kpB] = cvtpk2(wl2.x, wl3.x);
        *(unsigned int*)&WtL[(4 * fqW + 1) * WS + kpB] = cvtpk2(wl2.y, wl3.y);
        *(unsigned int*)&WtL[(4 * fqW + 2) * WS + kpB] = cvtpk2(wl2.z, wl3.z);
        *(unsigned int*)&WtL[(4 * fqW + 3) * WS + kpB] = cvtpk2(wl2.w, wl3.w);
        // write gathered-h tile rows
        *(uint2*)&Ht[(eH +   0) * WS + qH] = make_uint2(cvtpk2(hg0.x, hg0.y), cvtpk2(hg0.z, hg0.w));
        *(uint2*)&Ht[(eH +  64) * WS + qH] = make_uint2(cvtpk2(hg1.x, hg1.y), cvtpk2(hg1.z, hg1.w));
        *(uint2*)&Ht[(eH + 128) * WS + qH] = make_uint2(cvtpk2(hg2.x, hg2.y), cvtpk2(hg2.z, hg2.w));
        *(uint2*)&Ht[(eH + 192) * WS + qH] = make_uint2(cvtpk2(hg3.x, hg3.y), cvtpk2(hg3.z, hg3.w));
        __syncthreads();                 // tile ready
        if (kt < 7) {                    // issue next tile's loads under MFMA
            const int nk = (kt + 1) * 32;
            LOADW(nk); LOADH(nk);
        }
        short8 bfr[8];
#pragma unroll
        for (int nf = 0; nf < 8; ++nf)
            bfr[nf] = *(const short8*)&Ht[(sgrp * 128 + nf * 16 + l16) * WS + g * 8];
#pragma unroll
        for (int mt = 0; mt < 4; ++mt) {
            short8 a = *(const short8*)&WtL[(w * 64 + mt * 16 + l16) * WS + g * 8];
#pragma unroll
            for (int nf = 0; nf < 8; ++nf)
                acc[mt][nf] = __builtin_amdgcn_mfma_f32_16x16x32_bf16(a, bfr[nf], acc[mt][nf], 0, 0, 0);
        }
    }
#undef LOADW
#undef LOADH

    // ---------------- scores from registers ---------------------------------
    const int c0s = cntL[2 * sgrp];
    const int c1s = cntL[2 * sgrp + 1];
    float grv0[16], grv1[16], awv[16];
#pragma unroll
    for (int mt = 0; mt < 4; ++mt)
#pragma unroll
        for (int p = 0; p < 4; ++p) {
            int j = mt * 4 + p;
            int f = w * 64 + mt * 16 + g * 4 + p;
            grv0[j] = grL[2 * sgrp][f];
            grv1[j] = grL[2 * sgrp + 1][f];
            awv[j] = attn_w[f & 31];
        }
#pragma unroll
    for (int nf = 0; nf < 8; ++nf) {
        int e = nf * 16 + l16;
        bool is0 = e < c0s;
        float ph[2] = {0.f, 0.f};
#pragma unroll
        for (int mt = 0; mt < 4; ++mt)
#pragma unroll
            for (int p = 0; p < 4; ++p) {
                int j = mt * 4 + p;
                float gv = is0 ? grv0[j] : grv1[j];
                float x = acc[mt][nf][p] + gv;
                float lr = fmaxf(x, SLOPE * x);
                ph[mt >> 1] = fmaf(awv[j], lr, ph[mt >> 1]);
            }
#pragma unroll
        for (int hh = 0; hh < 2; ++hh) {
            float v = ph[hh];
            v += __shfl_xor(v, 16);
            v += __shfl_xor(v, 32);
            if (lane < 16) scp[sgrp][2 * w + hh][e] = v;
        }
    }
    __syncthreads();

    // ---------------- softmax in place (wave ww -> row ww&3) ----------------
    {
        const int r = ww & 3;
        const int sr = r >> 1;
        const int eb = (r & 1) ? cntL[2 * sr] : 0;
        const int cr = cntL[r];
        const bool valid = lane < cr;
        const int eidx = eb + (valid ? lane : 0);
        const int hb = (ww >> 2) * 4;
#pragma unroll
        for (int hq = 0; hq < 4; ++hq) {
            float sv = valid ? scp[sr][hb + hq][eidx] : -3e38f;
            float mx = sv;
#pragma unroll
            for (int d = 1; d < 64; d <<= 1) mx = fmaxf(mx, __shfl_xor(mx, d));
            float ev = valid ? __expf(sv - mx) : 0.f;
            float sm = ev;
#pragma unroll
            for (int d = 1; d < 64; d <<= 1) sm += __shfl_xor(sm, d);
            if (valid) scp[sr][hb + hq][eidx] = ev / sm;
        }
    }
    __syncthreads();

    // ---------------- aggregation from registers ----------------------------
    float av0[2][8], av1[2][8];
#pragma unroll
    for (int nf = 0; nf < 8; ++nf) {
        int e = nf * 16 + l16;
        bool in0 = e < c0s;
        bool in1 = (e >= c0s) && (e < c0s + c1s);
#pragma unroll
        for (int hh = 0; hh < 2; ++hh) {
            float a = scp[sgrp][2 * w + hh][e];
            av0[hh][nf] = in0 ? a : 0.f;
            av1[hh][nf] = in1 ? a : 0.f;
        }
    }
#pragma unroll
    for (int mt = 0; mt < 4; ++mt) {
        float o0[4], o1[4];
#pragma unroll
        for (int p = 0; p < 4; ++p) {
            float v0 = 0.f, v1 = 0.f;
#pragma unroll
            for (int nf = 0; nf < 8; ++nf) {
                v0 = fmaf(av0[mt >> 1][nf], acc[mt][nf][p], v0);
                v1 = fmaf(av1[mt >> 1][nf], acc[mt][nf][p], v1);
            }
#pragma unroll
            for (int d = 1; d < 16; d <<= 1) {
                v0 += __shfl_xor(v0, d);
                v1 += __shfl_xor(v1, d);
            }
            o0[p] = v0; o1[p] = v1;
        }
        if (l16 == 0) {
            const int f0 = w * 64 + mt * 16 + g * 4;
            *(float4*)&out[(size_t)(rbase + 2 * sgrp) * EMBED + f0] =
                make_float4(o0[0], o0[1], o0[2], o0[3]);
            *(float4*)&out[(size_t)(rbase + 2 * sgrp + 1) * EMBED + f0] =
                make_float4(o1[0], o1[1], o1[2], o1[3]);
        }
    }
}

extern "C" void kernel_launch(void* const* d_in, const int* in_sizes, int n_in,
                              void* d_out, int out_size, void* d_ws, size_t ws_size,
                              hipStream_t stream) {
    const float* h  = (const float*)d_in[0];
    const int*   ei = (const int*)d_in[1];
    const float* Wl = (const float*)d_in[2];
    const float* Wr = (const float*)d_in[3];
    const float* aw = (const float*)d_in[4];
    float* out = (float*)d_out;
    const int E = in_sizes[1] / 2;

    k_all<<<256, 512, 0, stream>>>(h, ei, E, Wl, Wr, aw, out);
}